// Round 5
// baseline (62.721 us; speedup 1.0000x reference)
//
#include <hip/hip_runtime.h>
#include <math.h>

#define BS 4
#define LQ 128
#define IMG 256
#define NPIX (IMG*IMG)
#define NQ 4
#define NSLICE 8
#define SLICE_PIX (NPIX/NSLICE)   // 8192
#define SLICE_F4 (SLICE_PIX/4)    // 2048
#define NBINS 128
#define CAP 512
#define NBLK (BS*(LQ/NQ)*NSLICE)  // 1024
#define SCALE (128.0f/3.0f)

__device__ __forceinline__ bool lessVI(float v1, int i1, float v2, int i2) {
    return (v1 < v2) || (v1 == v2 && i1 < i2);
}

#define CE8(WV, WI, a, c)                                                     \
    do {                                                                      \
        if (lessVI((WV)[c], (WI)[c], (WV)[a], (WI)[a])) {                     \
            float tv_ = (WV)[a]; (WV)[a] = (WV)[c]; (WV)[c] = tv_;            \
            int   ti_ = (WI)[a]; (WI)[a] = (WI)[c]; (WI)[c] = ti_;            \
        }                                                                     \
    } while (0)

// merge two sorted-ascending 8-lists -> sorted 8 smallest of 16 (static idx)
#define MERGE8(AV, AI, BV, BI, OV, OI)                                        \
    do {                                                                      \
        _Pragma("unroll")                                                     \
        for (int k_ = 0; k_ < 8; ++k_) {                                      \
            if (lessVI((AV)[k_], (AI)[k_], (BV)[7-k_], (BI)[7-k_])) {         \
                (OV)[k_] = (AV)[k_]; (OI)[k_] = (AI)[k_];                     \
            } else { (OV)[k_] = (BV)[7-k_]; (OI)[k_] = (BI)[7-k_]; }          \
        }                                                                     \
        CE8(OV, OI, 0, 4); CE8(OV, OI, 1, 5); CE8(OV, OI, 2, 6); CE8(OV, OI, 3, 7); \
        CE8(OV, OI, 0, 2); CE8(OV, OI, 1, 3); CE8(OV, OI, 4, 6); CE8(OV, OI, 5, 7); \
        CE8(OV, OI, 0, 1); CE8(OV, OI, 2, 3); CE8(OV, OI, 4, 5); CE8(OV, OI, 6, 7); \
    } while (0)

// 1024 blocks x 512 threads. Block = (batch b, query-quad qg, slice sl).
// A: histogram 1024 sampled sims/query -> tau bin B (cum>=8).
// B: scan slice once, 4 sims per pixel, append s*SCALE < B+1 candidates.
// C: exact lexicographic top-8 per (query,slice) -> global ws (sorted).
// Last-arriving block (device-scope ticket) merges 8 slice lists per query
// exactly and computes the loss.
__global__ __launch_bounds__(512)
void fused_kernel(const float* __restrict__ pred,
                  const float* __restrict__ imgs,
                  float2* __restrict__ ws,
                  int* __restrict__ counter,
                  float* __restrict__ out) {
    __shared__ float pool[NQ][3];
    __shared__ int   hist[NQ][NBINS];
    __shared__ int   Bq[NQ];
    __shared__ int   cnt[NQ];
    __shared__ float lv[NQ][CAP];
    __shared__ int   li[NQ][CAP];
    __shared__ float mv[NQ][2][8];
    __shared__ int   mi[NQ][2][8];
    __shared__ int   lastflag;
    __shared__ float red[512];

    const int bid = blockIdx.x;
    // XCD swizzle: bid%8 ~ XCD; 2 XCD slots per batch -> image L2-resident.
    const int b  = (bid & 7) >> 1;
    const int u  = bid >> 3;
    const int sl = u & (NSLICE - 1);
    const int qg = (u >> 3) | ((bid & 1) << 4);     // [0,32)
    const int tid = threadIdx.x;
    const int qi = tid >> 7;                        // query group [0,4)
    const int st = tid & 127;

    ((int*)hist)[tid] = 0;                          // 4*128 = 512 ints
    if (tid < NQ) cnt[tid] = 0;

    // pooled color (reshape quirk: flat row n = l*BS + b of preds(bs*L,2))
    const int l  = qg * NQ + qi;
    const int n  = l * BS + b;
    const int pb = n >> 7;
    const int pl = n & (LQ - 1);
    const float gx = pred[(pb * LQ + pl) * 8 + 0];
    const float gy = pred[(pb * LQ + pl) * 8 + 1];
    const int ix = (int)fminf(fmaxf(rintf(gx * 256.0f - 0.5f), 0.0f), 255.0f);
    const int iy = (int)fminf(fmaxf(rintf(gy * 256.0f - 0.5f), 0.0f), 255.0f);
    const float* img = imgs + b * 3 * NPIX;
    const int pc = iy * IMG + ix;
    const float c0 = img[pc];
    const float c1 = img[NPIX + pc];
    const float c2 = img[2 * NPIX + pc];
    if (st == 0) { pool[qi][0] = c0; pool[qi][1] = c1; pool[qi][2] = c2; }
    __syncthreads();

    // ---- Phase A: 1024 coalesced samples per query -> histogram
#pragma unroll
    for (int j = 0; j < 8; ++j) {
        const int p = sl * SLICE_PIX + j * 1024 + st;
        const float s = fabsf(img[p] - c0) + fabsf(img[NPIX + p] - c1)
                      + fabsf(img[2 * NPIX + p] - c2);
        int bn = (int)(s * SCALE);
        bn = bn > (NBINS - 1) ? (NBINS - 1) : bn;
        atomicAdd(&hist[qi][bn], 1);
    }
    __syncthreads();
    if (tid < NQ) {
        int cum = 0, bn = 0;
        while (bn < NBINS && cum < 8) { cum += hist[tid][bn]; ++bn; }
        Bq[tid] = bn - 1;    // cum count over bins 0..Bq >= 8
    }
    __syncthreads();

    float P0[NQ], P1[NQ], P2[NQ], T[NQ];
#pragma unroll
    for (int q = 0; q < NQ; ++q) {
        P0[q] = pool[q][0]; P1[q] = pool[q][1]; P2[q] = pool[q][2];
        const int B = Bq[q];
        // s*SCALE < B+1  <=>  (int)(s*SCALE) <= B  (exact, same quantization)
        T[q] = (B >= NBINS - 1) ? 3.0e38f : (float)(B + 1);
    }

    // ---- Phase B: scan slice once, 4 queries per pixel
    const float4* i0 = (const float4*)img;
    const float4* i1 = (const float4*)(img + NPIX);
    const float4* i2 = (const float4*)(img + 2 * NPIX);
#pragma unroll
    for (int it = 0; it < SLICE_F4 / 512; ++it) {
        const int q4 = sl * SLICE_F4 + it * 512 + tid;
        const float4 a0 = i0[q4];
        const float4 a1 = i1[q4];
        const float4 a2 = i2[q4];
        const int p = q4 * 4;
#define PX(vx, vy, vz, pp)                                                    \
        do {                                                                  \
            _Pragma("unroll")                                                 \
            for (int q = 0; q < NQ; ++q) {                                    \
                const float s = fabsf((vx) - P0[q]) + fabsf((vy) - P1[q])     \
                              + fabsf((vz) - P2[q]);                          \
                if (s * SCALE < T[q]) {                                       \
                    const int pos = atomicAdd(&cnt[q], 1);                    \
                    if (pos < CAP) { lv[q][pos] = s; li[q][pos] = (pp); }     \
                }                                                             \
            }                                                                 \
        } while (0)
        PX(a0.x, a1.x, a2.x, p + 0);
        PX(a0.y, a1.y, a2.y, p + 1);
        PX(a0.z, a1.z, a2.z, p + 2);
        PX(a0.w, a1.w, a2.w, p + 3);
#undef PX
    }
    __syncthreads();

    // ---- Phase C: exact top-8 per query; 2 waves per query
    const int wid  = tid >> 6;
    const int lane = tid & 63;
    {
        const int q    = wid >> 1;
        const int half = wid & 1;
        const int nels = min(cnt[q], CAP);
        float bv[8]; int bi[8];
#pragma unroll
        for (int k = 0; k < 8; ++k) { bv[k] = 3.0e38f; bi[k] = 0x7FFFFFFF; }
        for (int c = half * 64 + lane; c < nels; c += 128) {
            const float v = lv[q][c];
            const int  id = li[q][c];
            if (lessVI(v, id, bv[7], bi[7])) {
                bv[7] = v; bi[7] = id;
#pragma unroll
                for (int k = 7; k > 0; --k) {
                    if (lessVI(bv[k], bi[k], bv[k - 1], bi[k - 1])) {
                        float tv = bv[k]; bv[k] = bv[k - 1]; bv[k - 1] = tv;
                        int   ti = bi[k]; bi[k] = bi[k - 1]; bi[k - 1] = ti;
                    }
                }
            }
        }
        // wave bitonic merge with (val, idx)
#pragma unroll
        for (int off = 1; off < 64; off <<= 1) {
            float ov[8]; int oi[8];
#pragma unroll
            for (int k = 0; k < 8; ++k) {
                ov[k] = __shfl_xor(bv[k], off, 64);
                oi[k] = __shfl_xor(bi[k], off, 64);
            }
            float w[8]; int wi[8];
#pragma unroll
            for (int k = 0; k < 8; ++k) {
                if (lessVI(bv[k], bi[k], ov[7 - k], oi[7 - k])) { w[k] = bv[k];     wi[k] = bi[k]; }
                else                                            { w[k] = ov[7 - k]; wi[k] = oi[7 - k]; }
            }
            CE8(w, wi, 0, 4); CE8(w, wi, 1, 5); CE8(w, wi, 2, 6); CE8(w, wi, 3, 7);
            CE8(w, wi, 0, 2); CE8(w, wi, 1, 3); CE8(w, wi, 4, 6); CE8(w, wi, 5, 7);
            CE8(w, wi, 0, 1); CE8(w, wi, 2, 3); CE8(w, wi, 4, 5); CE8(w, wi, 6, 7);
#pragma unroll
            for (int k = 0; k < 8; ++k) { bv[k] = w[k]; bi[k] = wi[k]; }
        }
        if (lane == 0) {
#pragma unroll
            for (int k = 0; k < 8; ++k) { mv[q][half][k] = bv[k]; mi[q][half][k] = bi[k]; }
        }
    }
    __syncthreads();

    // merge the two halves, write sorted 8 to ws[(mq*NSLICE + sl)*8 ..]
    if (st == 0) {
        float av[8], bv2[8], ov[8]; int ai[8], bi2[8], oi[8];
#pragma unroll
        for (int k = 0; k < 8; ++k) {
            av[k] = mv[qi][0][k]; ai[k] = mi[qi][0][k];
            bv2[k] = mv[qi][1][k]; bi2[k] = mi[qi][1][k];
        }
        MERGE8(av, ai, bv2, bi2, ov, oi);
        const int mq = b * LQ + qg * NQ + qi;
        float2* o = ws + (mq * NSLICE + sl) * 8;
#pragma unroll
        for (int k = 0; k < 8; ++k) {
            float2 e; e.x = ov[k]; e.y = __int_as_float(oi[k]);
            o[k] = e;
        }
    }
    __syncthreads();

    // ---- device-scope ticket: last arrival does the loss epilogue
    if (tid == 0) {
        __threadfence();
        const int t = atomicAdd(counter, 1);
        lastflag = ((t % NBLK) == (NBLK - 1)) ? 1 : 0;
    }
    __syncthreads();
    if (!lastflag) return;
    __threadfence();

    // epilogue: thread t -> (b2, l2); merge 8 sorted slice lists, min-dist
    {
        const int b2 = tid >> 7;
        const int l2 = tid & (LQ - 1);
        float v = 0.0f;
        if (l2 >= 1) {
            const int mq = b2 * LQ + (l2 - 1);
            const float2* base = ws + mq * (NSLICE * 8);
            float fv[8]; int fi[8];
#pragma unroll
            for (int k = 0; k < 8; ++k) {
                const float2 e = base[k];
                fv[k] = e.x; fi[k] = __float_as_int(e.y);
            }
#pragma unroll
            for (int s2 = 1; s2 < NSLICE; ++s2) {
                float av[8], ov[8]; int ai[8], oi[8];
#pragma unroll
                for (int k = 0; k < 8; ++k) {
                    const float2 e = base[s2 * 8 + k];
                    av[k] = e.x; ai[k] = __float_as_int(e.y);
                }
                MERGE8(fv, fi, av, ai, ov, oi);
#pragma unroll
                for (int k = 0; k < 8; ++k) { fv[k] = ov[k]; fi[k] = oi[k]; }
            }
            const float qx = pred[(b2 * LQ + l2) * 8 + 0];
            const float qy = pred[(b2 * LQ + l2) * 8 + 1];
            float best = 3.0e38f;
#pragma unroll
            for (int k = 0; k < 8; ++k) {
                const int id = fi[k];
                const float tx = (float)(id & (IMG - 1)) * (1.0f / IMG);
                const float ty = (float)(id >> 8)        * (1.0f / IMG);
                const float dx = qx - tx;
                const float dy = qy - ty;
                best = fminf(best, sqrtf(dx * dx + dy * dy));
            }
            v = best;
        }
        red[tid] = v;
        __syncthreads();
        for (int s = 256; s > 0; s >>= 1) {
            if (tid < s) red[tid] += red[tid + s];
            __syncthreads();
        }
        if (tid == 0) out[0] = red[0] * (1.0f / (BS * (LQ - 1)));
    }
}

extern "C" void kernel_launch(void* const* d_in, const int* in_sizes, int n_in,
                              void* d_out, int out_size, void* d_ws, size_t ws_size,
                              hipStream_t stream) {
    const float* pred = (const float*)d_in[0];   // (4,128,8) f32
    const float* imgs = (const float*)d_in[1];   // (4,3,256,256) f32
    float* out = (float*)d_out;                  // scalar f32
    int* counter = (int*)d_ws;                   // 4B ticket counter
    float2* ws = (float2*)((char*)d_ws + 256);   // 512*8*8 float2 = 256 KB

    hipMemsetAsync(counter, 0, 4, stream);
    hipLaunchKernelGGL(fused_kernel, dim3(NBLK), dim3(512), 0, stream,
                       pred, imgs, ws, counter, out);
}